// Round 5
// baseline (374.637 us; speedup 1.0000x reference)
//
#include <hip/hip_runtime.h>
#include <hip/hip_bf16.h>

#define BB 32
#define TT 1500
#define DD 512
#define AA 512
#define HH 4
#define CC 10
#define KK 100
#define KW 201
#define MM (BB*TT)
#define PS 2.8853900817779268f   // 2/ln2: tanh(x) = 1 - 2*rcp(1+exp2(PS*x))

typedef unsigned short u16;
typedef unsigned int u32;
typedef __attribute__((ext_vector_type(8))) short bf16x8;
typedef __attribute__((ext_vector_type(4))) float f32x4;
typedef __attribute__((ext_vector_type(4))) unsigned int u32x4;

static __device__ __forceinline__ u16 f2bf(float f) {
    u32 x = __float_as_uint(f);
    return (u16)((x + 0x7fffu + ((x >> 16) & 1u)) >> 16);   // RNE
}
static __device__ __forceinline__ u32 pkbf(float lo, float hi) {
    u32 r;
    asm("v_cvt_pk_bf16_f32 %0, %1, %2" : "=v"(r) : "v"(lo), "v"(hi));
    return r;
}
static __device__ __forceinline__ void stage16(const void* g, void* l) {
    __builtin_amdgcn_global_load_lds(
        (const __attribute__((address_space(1))) void*)g,
        (__attribute__((address_space(3))) void*)l, 16, 0, 0);
}

// =================== prep: wencT(+PS), dec_ps, conv, zero ctx/out ===========
__global__ __launch_bounds__(256) void prep_k(
    const float* __restrict__ wencW, const float* __restrict__ q,
    const float* __restrict__ wdec, const float* __restrict__ encb,
    const float* __restrict__ aw, const float* __restrict__ convW,
    u16* __restrict__ wenc_t, float* __restrict__ dec_ps,
    float* __restrict__ cfeat, float* __restrict__ ctx, float* __restrict__ outz)
{
    __shared__ float pls[4160];
    int blk = blockIdx.x, tid = threadIdx.x;
    if (blk < 64) {
        // transpose + PS-scale w_enc -> bf16 [A][D], 64x64 tile per block
        int a0 = (blk & 7) * 64, d0 = (blk >> 3) * 64;
#pragma unroll
        for (int it = 0; it < 16; ++it) {
            int row = it * 4 + (tid >> 6), col = tid & 63;
            pls[row * 65 + col] = wencW[(size_t)(d0 + row) * AA + a0 + col];
        }
        __syncthreads();
#pragma unroll
        for (int it = 0; it < 16; ++it) {
            int ar = it * 4 + (tid >> 6), dc = tid & 63;
            wenc_t[(size_t)(a0 + ar) * DD + d0 + dc] = f2bf(pls[dc * 65 + ar] * PS);
        }
    } else if (blk < 128) {
        // dec_ps[b][a] = PS*(encb[a] + q[b]·wdec[:,a])
        int bidx = blk - 64;
        int b = bidx >> 1, a = (bidx & 1) * 256 + tid;
        for (int i = tid; i < DD; i += 256) pls[i] = q[b * DD + i];
        __syncthreads();
        float acc = encb[a];
#pragma unroll 8
        for (int d = 0; d < DD; ++d) acc = fmaf(pls[d], wdec[(size_t)d * AA + a], acc);
        dec_ps[b * AA + a] = acc * PS;
    } else if (blk < 384) {
        // grouped conv1d -> cfeat[h][b*T+t][10]; 2 blocks per (h,b)
        int cidx = blk - 128;
        int half = cidx & 1, hb = cidx >> 1;
        int h = hb >> 5, b = hb & 31;
        float* srow = pls;            // 952
        float* swk  = pls + 952;      // 2010
        int tstart = half * 750;
        const float* arow = aw + (size_t)(h * BB + b) * TT;
        for (int i = tid; i < 952; i += 256) {
            int t = tstart + i - KK;
            srow[i] = (t >= 0 && t < TT) ? arow[t] : 0.f;
        }
        for (int i = tid; i < CC * KW; i += 256) swk[i] = convW[h * CC * KW + i];
        __syncthreads();
        if (tid < 250) {
            int tl = tid * 3;
            float acc[CC][3];
#pragma unroll
            for (int c = 0; c < CC; ++c)
#pragma unroll
                for (int u = 0; u < 3; ++u) acc[c][u] = 0.f;
            float r0 = srow[tl], r1 = srow[tl + 1], r2 = srow[tl + 2];
            for (int j = 0; j < KW; ++j) {
#pragma unroll
                for (int c = 0; c < CC; ++c) {
                    float w = swk[c * KW + j];
                    acc[c][0] = fmaf(r0, w, acc[c][0]);
                    acc[c][1] = fmaf(r1, w, acc[c][1]);
                    acc[c][2] = fmaf(r2, w, acc[c][2]);
                }
                r0 = r1; r1 = r2; r2 = srow[tl + j + 3];
            }
            float* dst = cfeat + ((size_t)h * MM + (size_t)b * TT + tstart + tl) * CC;
#pragma unroll
            for (int u = 0; u < 3; ++u)
#pragma unroll
                for (int c = 0; c < CC; ++c) dst[u * CC + c] = acc[c][u];
        }
    } else if (blk < 392) {
        float4* p = (float4*)ctx;
        int bidx = blk - 384;
        float4 z = {0.f, 0.f, 0.f, 0.f};
#pragma unroll
        for (int k2 = 0; k2 < 8; ++k2) p[bidx * 2048 + k2 * 256 + tid] = z;
    } else {
        float4* p = (float4*)outz;
        int bidx = blk - 392;
        float4 z = {0.f, 0.f, 0.f, 0.f};
#pragma unroll
        for (int k2 = 0; k2 < 8; ++k2) p[bidx * 2048 + k2 * 256 + tid] = z;
    }
}

// =================== fused GEMM + head-MFMA + e-epilogue ====================
// Double-buffered LDS, 1 barrier/K-step (T3-min 2-phase); B in k-chunk-major
// LDS layout (conflict-free ds_read_b128 via pre-permuted global src).
// acc = PS*(key·wenc); per head t4 = mfma([cf|sel],[wconvPS|decPS],acc);
// Q4[bn][h][row] = sum_col v * rcp(1+exp2(t4)).
__global__ __launch_bounds__(256) void gemm_e_k(
    const float* __restrict__ key, const u16* __restrict__ Bt,
    const float* __restrict__ dec_ps, const float* __restrict__ cf,
    const float* __restrict__ wconv, const float* __restrict__ vw,
    float* __restrict__ Q4)
{
    // buffers: A0@0 (10240), B0@10240 (8192), A1@18432 (10240), B1@28672 (8192)
    // epilogue reuse: sAe@0 (16384), sBe@16384 (4096); ZPAD@36864 (16B)
    __shared__ u32x4 smem4[2305];        // 36880 B
    char* smem = (char*)smem4;

    int tid = threadIdx.x;
    int orig = blockIdx.x;
    int xcd = orig & 7, idx = orig >> 3;               // bijective m204 swizzle
    int swz = (xcd < 4 ? xcd * 188 : 752 + (xcd - 4) * 187) + idx;
    int bn = swz & 3, bm = swz >> 2;
    int row0 = bm * 128, col0 = bn * 128;
    int lane = tid & 63;
    int wv = tid >> 6;
    int wr = wv >> 1, wc = wv & 1;
    int lhi = lane >> 4, llo = lane & 15;

    f32x4 acc[4][4];
#pragma unroll
    for (int i = 0; i < 4; ++i)
#pragma unroll
        for (int j = 0; j < 4; ++j) acc[i][j] = (f32x4){0.f, 0.f, 0.f, 0.f};

    // A staging: thread = (row=tid>>1, 32B-half=tid&1); LDS row stride 80B
    const float4* gA = (const float4*)(key + (size_t)(row0 + (tid >> 1)) * DD) + (tid & 1) * 4;
    u32 aWoff = (tid >> 1) * 80 + (tid & 1) * 32;
    // B staging: k-chunk-major [kc][col][8k]; per-lane global src permuted
    const u16* gBa = Bt + (size_t)(col0 + (tid & 127)) * DD + (tid >> 7) * 8;  // kc = tid>>7 (0..1)
    const u16* gBb = gBa + 16;                                                  // kc + 2

    auto loadPA = [&](float4& a0, float4& a1, float4& a2, float4& a3, int s) {
        a0 = gA[s * 8]; a1 = gA[s * 8 + 1]; a2 = gA[s * 8 + 2]; a3 = gA[s * 8 + 3];
    };
    auto stageB = [&](int s, int bbyte) {
        stage16(gBa + s * 32, (u16*)(smem + bbyte) + (size_t)tid * 8);
        stage16(gBb + s * 32, (u16*)(smem + bbyte + 4096) + (size_t)tid * 8);
    };
    auto writeA = [&](int abyte, float4 q0, float4 q1, float4 q2, float4 q3) {
        u32x4 s0, s1;
        s0.x = pkbf(q0.x, q0.y); s0.y = pkbf(q0.z, q0.w);
        s0.z = pkbf(q1.x, q1.y); s0.w = pkbf(q1.z, q1.w);
        s1.x = pkbf(q2.x, q2.y); s1.y = pkbf(q2.z, q2.w);
        s1.z = pkbf(q3.x, q3.y); s1.w = pkbf(q3.z, q3.w);
        *(u32x4*)(smem + abyte + aWoff) = s0;
        *(u32x4*)(smem + abyte + aWoff + 16) = s1;
    };
    auto kstep = [&](int aoff, int boff) {
        bf16x8 af[4], bfr[4];
#pragma unroll
        for (int i = 0; i < 4; ++i)
            af[i] = *(const bf16x8*)(smem + aoff + (wr * 64 + i * 16 + llo) * 80 + lhi * 16);
#pragma unroll
        for (int j = 0; j < 4; ++j)
            bfr[j] = *(const bf16x8*)(smem + boff + (wc * 64 + j * 16 + llo) * 16 + lhi * 2048);
#pragma unroll
        for (int i = 0; i < 4; ++i)
#pragma unroll
            for (int j = 0; j < 4; ++j)
                acc[i][j] = __builtin_amdgcn_mfma_f32_16x16x32_bf16(
                    af[i], bfr[j], acc[i][j], 0, 0, 0);
    };

    float4 e0, e1, e2, e3, o0, o1, o2, o3;
    // prologue: stage step0 into buf0; prefetch steps 1 (odd) and 2 (even)
    loadPA(e0, e1, e2, e3, 0);
    stageB(0, 10240);
    writeA(0, e0, e1, e2, e3);
    loadPA(o0, o1, o2, o3, 1);
    loadPA(e0, e1, e2, e3, 2);
    __syncthreads();

#pragma unroll
    for (int t = 0; t < 16; t += 2) {
        // even step t: compute buf0, stage step t+1 -> buf1
        stageB(t + 1, 28672);
        writeA(18432, o0, o1, o2, o3);
        if (t + 3 < 16) loadPA(o0, o1, o2, o3, t + 3);
        kstep(0, 10240);
        __syncthreads();
        // odd step t+1: compute buf1, stage step t+2 -> buf0
        if (t + 2 < 16) {
            stageB(t + 2, 10240);
            writeA(0, e0, e1, e2, e3);
            if (t + 4 < 16) loadPA(e0, e1, e2, e3, t + 4);
        }
        kstep(18432, 28672);
        __syncthreads();
    }

    // ---- stage extension tiles (smem reuse; all K-loop reads fenced above) ----
    const int ZPAD = 36864;
    int b0 = row0 / TT;
    int boundary = (b0 + 1) * TT - row0;
    int b1 = min(b0 + 1, BB - 1);
    {
        // sAe[h][128 rows][16k]: k0..9=cf, k10=sel_b0, k11=sel_b1, k12..15=0
        int h = tid >> 6;
#pragma unroll
        for (int e = 0; e < 2; ++e) {
            int r = (tid & 63) * 2 + e;
            const float2* cp = (const float2*)(cf + ((size_t)h * MM + row0 + r) * CC);
            float2 c0 = cp[0], c1 = cp[1], c2 = cp[2], c3 = cp[3], c4 = cp[4];
            u32x4 lo, hi;
            lo.x = pkbf(c0.x, c0.y); lo.y = pkbf(c1.x, c1.y);
            lo.z = pkbf(c2.x, c2.y); lo.w = pkbf(c3.x, c3.y);
            hi.x = pkbf(c4.x, c4.y);
            hi.y = (r < boundary) ? 0x00003f80u : 0x3f800000u;  // (sel0,sel1) bf16
            hi.z = 0u; hi.w = 0u;
            char* dst = smem + (h * 128 + r) * 32;
            *(u32x4*)dst = lo;
            *(u32x4*)(dst + 16) = hi;
        }
        // sBe[128 cols][16k]: k0..9=wconv*PS, k10=dec_ps[b0], k11=dec_ps[b1]
        int col = tid >> 1, kh = tid & 1;
        u32x4 w;
        if (kh == 0) {
            float v0 = wconv[0 * AA + col0 + col] * PS, v1 = wconv[1 * AA + col0 + col] * PS;
            float v2 = wconv[2 * AA + col0 + col] * PS, v3 = wconv[3 * AA + col0 + col] * PS;
            float v4 = wconv[4 * AA + col0 + col] * PS, v5 = wconv[5 * AA + col0 + col] * PS;
            float v6 = wconv[6 * AA + col0 + col] * PS, v7 = wconv[7 * AA + col0 + col] * PS;
            w.x = pkbf(v0, v1); w.y = pkbf(v2, v3); w.z = pkbf(v4, v5); w.w = pkbf(v6, v7);
        } else {
            float v8 = wconv[8 * AA + col0 + col] * PS, v9 = wconv[9 * AA + col0 + col] * PS;
            float d0v = dec_ps[b0 * AA + col0 + col], d1v = dec_ps[b1 * AA + col0 + col];
            w.x = pkbf(v8, v9); w.y = pkbf(d0v, d1v); w.z = 0u; w.w = 0u;
        }
        *(u32x4*)(smem + 16384 + col * 32 + kh * 16) = w;
        if (tid == 0) { *(u32x4*)(smem + ZPAD) = (u32x4){0u, 0u, 0u, 0u}; }
    }
    __syncthreads();

    // ---- head-steps + epilogue ----
    float svj[4];
    bf16x8 be[4];
#pragma unroll
    for (int j = 0; j < 4; ++j) {
        int col = wc * 64 + j * 16 + llo;
        svj[j] = vw[col0 + col];
        u32 off = (lhi < 2) ? (16384u + col * 32 + lhi * 16) : (u32)ZPAD;
        be[j] = *(const bf16x8*)(smem + off);
    }
#pragma unroll
    for (int h = 0; h < 4; ++h) {
#pragma unroll
        for (int i = 0; i < 4; ++i) {
            int rowA = h * 128 + wr * 64 + i * 16 + llo;
            u32 offa = (lhi < 2) ? (rowA * 32 + lhi * 16) : (u32)ZPAD;
            bf16x8 ae = *(const bf16x8*)(smem + offa);
            float ep[4] = {0.f, 0.f, 0.f, 0.f};
#pragma unroll
            for (int j = 0; j < 4; ++j) {
                f32x4 t4 = __builtin_amdgcn_mfma_f32_16x16x32_bf16(ae, be[j], acc[i][j], 0, 0, 0);
#pragma unroll
                for (int r = 0; r < 4; ++r) {
                    float z = exp2f(t4[r]);
                    float p = __builtin_amdgcn_rcpf(1.f + z);
                    ep[r] = fmaf(svj[j], p, ep[r]);
                }
            }
#pragma unroll
            for (int r = 0; r < 4; ++r) {
                float s = ep[r];
                s += __shfl_xor(s, 1);
                s += __shfl_xor(s, 2);
                s += __shfl_xor(s, 4);
                s += __shfl_xor(s, 8);
                if (llo == 0)
                    Q4[((size_t)(bn * HH + h)) * MM + row0 + wr * 64 + i * 16 + lhi * 4 + r] = s;
            }
        }
    }
}

// =================== fin: softmax (blk<128) | ctx (blk>=128) =================
__global__ __launch_bounds__(256) void fin_k(
    const float* __restrict__ Q4, const int* __restrict__ klen,
    const float* __restrict__ aw, const float* __restrict__ value,
    float* __restrict__ aw_new, float* __restrict__ ctx)
{
    __shared__ float fls[1512];
    int blk = blockIdx.x, tid = threadIdx.x;
    if (blk < 128) {
        int h = blk >> 5, b = blk & 31;
        int len = klen[b];
        const float* q0 = Q4 + (size_t)(0 * HH + h) * MM + (size_t)b * TT;
        const float* q1 = Q4 + (size_t)(1 * HH + h) * MM + (size_t)b * TT;
        const float* q2 = Q4 + (size_t)(2 * HH + h) * MM + (size_t)b * TT;
        const float* q3 = Q4 + (size_t)(3 * HH + h) * MM + (size_t)b * TT;
        float* orow = aw_new + (size_t)(h * BB + b) * TT;
        float* rbuf = fls + 1500;
        int lane = tid & 63, wvv = tid >> 6;
        float mx = -3.4e38f;
        for (int t = tid; t < len; t += 256) {
            float e = -2.f * (q0[t] + q1[t] + q2[t] + q3[t]);
            fls[t] = e;
            mx = fmaxf(mx, e);
        }
#pragma unroll
        for (int off = 32; off; off >>= 1) mx = fmaxf(mx, __shfl_xor(mx, off));
        if (lane == 0) rbuf[wvv] = mx;
        __syncthreads();
        mx = fmaxf(fmaxf(rbuf[0], rbuf[1]), fmaxf(rbuf[2], rbuf[3]));
        float sum = 0.f;
        for (int t = tid; t < len; t += 256) {
            float p = __expf(fls[t] - mx);
            fls[t] = p; sum += p;
        }
#pragma unroll
        for (int off = 32; off; off >>= 1) sum += __shfl_xor(sum, off);
        if (lane == 0) rbuf[4 + wvv] = sum;
        __syncthreads();
        float inv = 1.f / (rbuf[4] + rbuf[5] + rbuf[6] + rbuf[7]);
        for (int t = tid; t < TT; t += 256) orow[t] = (t < len) ? fls[t] * inv : 0.f;
    } else {
        int cidx = blk - 128;
        int b = cidx / 25, chunk = cidx - b * 25;
        int c0 = chunk * 60;
        float (*sw)[60] = (float(*)[60])fls;
        if (tid < 240)
            sw[tid / 60][tid % 60] = aw[(size_t)((tid / 60) * BB + b) * TT + c0 + (tid % 60)];
        __syncthreads();
        float a00 = 0, a01 = 0, a10 = 0, a11 = 0, a20 = 0, a21 = 0, a30 = 0, a31 = 0;
        const float* vp = value + ((size_t)b * TT + c0) * DD;
        for (int t = 0; t < 60; ++t) {
            float v0 = vp[(size_t)t * DD + tid];
            float v1 = vp[(size_t)t * DD + tid + 256];
            a00 = fmaf(sw[0][t], v0, a00); a01 = fmaf(sw[0][t], v1, a01);
            a10 = fmaf(sw[1][t], v0, a10); a11 = fmaf(sw[1][t], v1, a11);
            a20 = fmaf(sw[2][t], v0, a20); a21 = fmaf(sw[2][t], v1, a21);
            a30 = fmaf(sw[3][t], v0, a30); a31 = fmaf(sw[3][t], v1, a31);
        }
        atomicAdd(&ctx[(b * HH + 0) * DD + tid], a00);
        atomicAdd(&ctx[(b * HH + 0) * DD + tid + 256], a01);
        atomicAdd(&ctx[(b * HH + 1) * DD + tid], a10);
        atomicAdd(&ctx[(b * HH + 1) * DD + tid + 256], a11);
        atomicAdd(&ctx[(b * HH + 2) * DD + tid], a20);
        atomicAdd(&ctx[(b * HH + 2) * DD + tid + 256], a21);
        atomicAdd(&ctx[(b * HH + 3) * DD + tid], a30);
        atomicAdd(&ctx[(b * HH + 3) * DD + tid + 256], a31);
    }
}

// =================== out[b][d] = ctx_flat[b]·w_out[:,d] + b_out[d] ==========
__global__ __launch_bounds__(512) void out_k(const float* __restrict__ ctx,
                                             const float* __restrict__ wout,
                                             const float* __restrict__ wob,
                                             float* __restrict__ out)
{
    int b0 = blockIdx.x * 4, kc = blockIdx.y;
    int tid = threadIdx.x;
    __shared__ float sc[4][64];
    if (tid < 256) sc[tid >> 6][tid & 63] =
        ctx[(size_t)(b0 + (tid >> 6)) * (HH * DD) + kc * 64 + (tid & 63)];
    __syncthreads();
    float acc0 = 0, acc1 = 0, acc2 = 0, acc3 = 0;
    const float* wp = wout + (size_t)(kc * 64) * DD + tid;
#pragma unroll 8
    for (int kk = 0; kk < 64; ++kk) {
        float w = wp[(size_t)kk * DD];
        acc0 = fmaf(sc[0][kk], w, acc0); acc1 = fmaf(sc[1][kk], w, acc1);
        acc2 = fmaf(sc[2][kk], w, acc2); acc3 = fmaf(sc[3][kk], w, acc3);
    }
    if (kc == 0) {
        float bb = wob[tid];
        acc0 += bb; acc1 += bb; acc2 += bb; acc3 += bb;
    }
    atomicAdd(&out[(b0 + 0) * DD + tid], acc0);
    atomicAdd(&out[(b0 + 1) * DD + tid], acc1);
    atomicAdd(&out[(b0 + 2) * DD + tid], acc2);
    atomicAdd(&out[(b0 + 3) * DD + tid], acc3);
}

extern "C" void kernel_launch(void* const* d_in, const int* in_sizes, int n_in,
                              void* d_out, int out_size, void* d_ws, size_t ws_size,
                              hipStream_t stream) {
    const float* key    = (const float*)d_in[0];
    const int*   klen   = (const int*)  d_in[1];
    const float* value  = (const float*)d_in[2];
    const float* query  = (const float*)d_in[3];
    const float* aw     = (const float*)d_in[4];
    const float* wencW  = (const float*)d_in[5];
    const float* wencb  = (const float*)d_in[6];
    const float* wdecW  = (const float*)d_in[7];
    const float* wconvW = (const float*)d_in[8];
    const float* vW     = (const float*)d_in[9];
    const float* convW  = (const float*)d_in[10];
    const float* woutW  = (const float*)d_in[11];
    const float* woutb  = (const float*)d_in[12];

    float* out    = (float*)d_out;                  // [B*D]
    float* aw_new = out + BB * DD;                  // [H*B*T]

    // workspace (~11.6 MB)
    char* ws = (char*)d_ws;
    u16*   wenc_t = (u16*)ws;                       //   524,288 B
    float* dec_ps = (float*)(ws + 524288);          //    65,536 B
    float* cfeat  = (float*)(ws + 589824);          // 7,680,000 B
    float* Q4     = (float*)(ws + 8269824);         // 3,072,000 B
    float* ctx    = (float*)(ws + 11341824);        //   262,144 B

    prep_k  <<<394, 256, 0, stream>>>(wencW, query, wdecW, wencb, aw, convW,
                                      wenc_t, dec_ps, cfeat, ctx, out);
    gemm_e_k<<<1500, 256, 0, stream>>>(key, wenc_t, dec_ps, cfeat, wconvW, vW, Q4);
    fin_k   <<<928, 256, 0, stream>>>(Q4, klen, aw, value, aw_new, ctx);
    out_k   <<<dim3(8, 32), 512, 0, stream>>>(ctx, woutW, woutb, out);
}

// Round 6
// 360.457 us; speedup vs baseline: 1.0393x; 1.0393x over previous
//
#include <hip/hip_runtime.h>
#include <hip/hip_bf16.h>

#define BB 32
#define TT 1500
#define DD 512
#define AA 512
#define HH 4
#define CC 10
#define KK 100
#define KW 201
#define MM (BB*TT)
#define PS 2.8853900817779268f   // 2/ln2: tanh(x) = 1 - 2*rcp(1+exp2(PS*x))

typedef unsigned short u16;
typedef unsigned int u32;
typedef __attribute__((ext_vector_type(8))) short bf16x8;
typedef __attribute__((ext_vector_type(4))) float f32x4;
typedef __attribute__((ext_vector_type(4))) unsigned int u32x4;

static __device__ __forceinline__ u16 f2bf(float f) {
    u32 x = __float_as_uint(f);
    return (u16)((x + 0x7fffu + ((x >> 16) & 1u)) >> 16);   // RNE
}
static __device__ __forceinline__ u32 pkbf(float lo, float hi) {
    u32 r;
    asm("v_cvt_pk_bf16_f32 %0, %1, %2" : "=v"(r) : "v"(lo), "v"(hi));
    return r;
}
static __device__ __forceinline__ void stage16(const void* g, void* l) {
    __builtin_amdgcn_global_load_lds(
        (const __attribute__((address_space(1))) void*)g,
        (__attribute__((address_space(3))) void*)l, 16, 0, 0);
}

// =================== prep: wencT(+PS), dec_ps, conv, zero ctx/out ===========
__global__ __launch_bounds__(256) void prep_k(
    const float* __restrict__ wencW, const float* __restrict__ q,
    const float* __restrict__ wdec, const float* __restrict__ encb,
    const float* __restrict__ aw, const float* __restrict__ convW,
    u16* __restrict__ wenc_t, float* __restrict__ dec_ps,
    float* __restrict__ cfeat, float* __restrict__ ctx, float* __restrict__ outz)
{
    __shared__ float pls[4160];
    int blk = blockIdx.x, tid = threadIdx.x;
    if (blk < 64) {
        // transpose + PS-scale w_enc -> bf16 [A][D], 64x64 tile per block
        int a0 = (blk & 7) * 64, d0 = (blk >> 3) * 64;
#pragma unroll
        for (int it = 0; it < 16; ++it) {
            int row = it * 4 + (tid >> 6), col = tid & 63;
            pls[row * 65 + col] = wencW[(size_t)(d0 + row) * AA + a0 + col];
        }
        __syncthreads();
#pragma unroll
        for (int it = 0; it < 16; ++it) {
            int ar = it * 4 + (tid >> 6), dc = tid & 63;
            wenc_t[(size_t)(a0 + ar) * DD + d0 + dc] = f2bf(pls[dc * 65 + ar] * PS);
        }
    } else if (blk < 128) {
        // dec_ps[b][a] = PS*(encb[a] + q[b]·wdec[:,a])
        int bidx = blk - 64;
        int b = bidx >> 1, a = (bidx & 1) * 256 + tid;
        for (int i = tid; i < DD; i += 256) pls[i] = q[b * DD + i];
        __syncthreads();
        float acc = encb[a];
#pragma unroll 8
        for (int d = 0; d < DD; ++d) acc = fmaf(pls[d], wdec[(size_t)d * AA + a], acc);
        dec_ps[b * AA + a] = acc * PS;
    } else if (blk < 896) {
        // grouped conv1d -> cfeat[h][b*T+t][10]; 6 chunk-blocks of 250 t per (h,b)
        int cidx = blk - 128;
        int hb = cidx / 6, chunk = cidx - hb * 6;
        int h = hb >> 5, b = hb & 31;
        float* srow = pls;            // 450
        float* swk  = pls + 456;      // 2010
        int tstart = chunk * 250;
        const float* arow = aw + (size_t)(h * BB + b) * TT;
        for (int i = tid; i < 450; i += 256) {
            int t = tstart + i - KK;
            srow[i] = (t >= 0 && t < TT) ? arow[t] : 0.f;
        }
        for (int i = tid; i < CC * KW; i += 256) swk[i] = convW[h * CC * KW + i];
        __syncthreads();
        if (tid < 250) {
            float acc[CC];
#pragma unroll
            for (int c = 0; c < CC; ++c) acc[c] = 0.f;
            for (int j = 0; j < KW; ++j) {
                float x = srow[tid + j];
#pragma unroll
                for (int c = 0; c < CC; ++c)
                    acc[c] = fmaf(x, swk[c * KW + j], acc[c]);
            }
            float* dst = cfeat + ((size_t)h * MM + (size_t)b * TT + tstart + tid) * CC;
#pragma unroll
            for (int c = 0; c < CC; ++c) dst[c] = acc[c];
        }
    } else if (blk < 904) {
        float4* p = (float4*)ctx;
        int bidx = blk - 896;
        float4 z = {0.f, 0.f, 0.f, 0.f};
#pragma unroll
        for (int k2 = 0; k2 < 8; ++k2) p[bidx * 2048 + k2 * 256 + tid] = z;
    } else {
        float4* p = (float4*)outz;
        int bidx = blk - 904;
        float4 z = {0.f, 0.f, 0.f, 0.f};
#pragma unroll
        for (int k2 = 0; k2 < 8; ++k2) p[bidx * 2048 + k2 * 256 + tid] = z;
    }
}

// =================== fused GEMM + head-MFMA + e-epilogue ====================
// 64x128 tile (grid 3000 for concurrency), BK=32, dbuf LDS with ONE barrier
// per K-step (T3-minimum). B k-chunk-major (conflict-free ds_read_b128).
// acc = PS*(key·wenc); per head t4 = mfma([cf|sel],[wconvPS|decPS],acc);
// Q4[bn][h][row] = sum_col v * rcp(1+exp2(t4)).
__global__ __launch_bounds__(256) void gemm_e_k(
    const float* __restrict__ key, const u16* __restrict__ Bt,
    const float* __restrict__ dec_ps, const float* __restrict__ cf,
    const float* __restrict__ wconv, const float* __restrict__ vw,
    float* __restrict__ Q4)
{
    // K-loop: A0@0(5120=64x80), A1@5120, B0@10240(8192), B1@18432(8192)
    // epilogue: sAe@0 [4][64]x48B=12288, sBe@12288 (128x48=6144) -> 18432
    // ZPAD@26624(16B); alloc 26640
    __shared__ u32x4 smem4[1665];
    char* smem = (char*)smem4;

    int tid = threadIdx.x;
    int orig = blockIdx.x;
    int xcd = orig & 7, idx = orig >> 3;   // bijective: 3000 = 8*375
    int swz = xcd * 375 + idx;
    int bn = swz & 3, bm = swz >> 2;       // bm 0..749
    int row0 = bm * 64, col0 = bn * 128;
    int lane = tid & 63, wv = tid >> 6;
    int wr = wv >> 1, wc = wv & 1;         // wave: rows wr*32..+31, cols wc*64..+63
    int lhi = lane >> 4, llo = lane & 15;

    f32x4 acc[2][4];
#pragma unroll
    for (int i = 0; i < 2; ++i)
#pragma unroll
        for (int j = 0; j < 4; ++j) acc[i][j] = (f32x4){0.f, 0.f, 0.f, 0.f};

    // A staging: thread = (row=tid>>2 of 64, qtr=tid&3); 8 f32 -> 16B bf16
    const float4* gA = (const float4*)(key + (size_t)(row0 + (tid >> 2)) * DD) + (tid & 3) * 2;
    u32 aWoff = (tid >> 2) * 80 + (tid & 3) * 16;
    // B staging: k-chunk-major [kc:4][col:128][16B]
    const u16* gBa = Bt + (size_t)(col0 + (tid & 127)) * DD + (tid >> 7) * 8;
    const u16* gBb = gBa + 16;

    auto stageB = [&](int s, int bbyte) {
        stage16(gBa + s * 32, (u16*)(smem + bbyte) + (size_t)tid * 8);
        stage16(gBb + s * 32, (u16*)(smem + bbyte + 4096) + (size_t)tid * 8);
    };
    auto writeA = [&](int abyte, float4 q0, float4 q1) {
        u32x4 s0;
        s0.x = pkbf(q0.x, q0.y); s0.y = pkbf(q0.z, q0.w);
        s0.z = pkbf(q1.x, q1.y); s0.w = pkbf(q1.z, q1.w);
        *(u32x4*)(smem + abyte + aWoff) = s0;
    };
    auto kstep = [&](int aoff, int boff) {
        bf16x8 af[2], bfr[4];
#pragma unroll
        for (int i = 0; i < 2; ++i)
            af[i] = *(const bf16x8*)(smem + aoff + (wr * 32 + i * 16 + llo) * 80 + lhi * 16);
#pragma unroll
        for (int j = 0; j < 4; ++j)
            bfr[j] = *(const bf16x8*)(smem + boff + (wc * 64 + j * 16 + llo) * 16 + lhi * 2048);
#pragma unroll
        for (int i = 0; i < 2; ++i)
#pragma unroll
            for (int j = 0; j < 4; ++j)
                acc[i][j] = __builtin_amdgcn_mfma_f32_16x16x32_bf16(
                    af[i], bfr[j], acc[i][j], 0, 0, 0);
    };

    // prologue: buf0 <- step0; prefetch A(1)
    float4 p0 = gA[0], p1 = gA[1];
    stageB(0, 10240);
    writeA(0, p0, p1);
    p0 = gA[8]; p1 = gA[9];
    __syncthreads();

#pragma unroll
    for (int t = 0; t < 16; ++t) {
        const int abuf_c = (t & 1) ? 5120 : 0;
        const int bbuf_c = (t & 1) ? 18432 : 10240;
        if (t < 15) {
            const int abuf_n = (t & 1) ? 0 : 5120;
            const int bbuf_n = (t & 1) ? 10240 : 18432;
            stageB(t + 1, bbuf_n);              // next tile in flight during compute
            writeA(abuf_n, p0, p1);             // A(t+1) regs -> alt buffer
            if (t < 14) { p0 = gA[(t + 2) * 8]; p1 = gA[(t + 2) * 8 + 1]; }
        }
        kstep(abuf_c, bbuf_c);
        __syncthreads();                        // ONE drain+barrier per K-step
    }

    // ---- stage extension tiles (48B-padded rows: conflict-free) ----
    const int ZPAD = 26624;
    int b0 = row0 / TT;
    int boundary = (b0 + 1) * TT - row0;
    int b1 = min(b0 + 1, BB - 1);
    {
        // sAe[h][64 rows][48B]: k0..9=cf, k10=sel_b0, k11=sel_b1, k12..15=0
        int h = tid >> 6, r = tid & 63;
        const float2* cp = (const float2*)(cf + ((size_t)h * MM + row0 + r) * CC);
        float2 c0 = cp[0], c1 = cp[1], c2 = cp[2], c3 = cp[3], c4 = cp[4];
        u32x4 lo, hi;
        lo.x = pkbf(c0.x, c0.y); lo.y = pkbf(c1.x, c1.y);
        lo.z = pkbf(c2.x, c2.y); lo.w = pkbf(c3.x, c3.y);
        hi.x = pkbf(c4.x, c4.y);
        hi.y = (r < boundary) ? 0x00003f80u : 0x3f800000u;  // (sel0,sel1) bf16
        hi.z = 0u; hi.w = 0u;
        char* dst = smem + (h * 64 + r) * 48;
        *(u32x4*)dst = lo;
        *(u32x4*)(dst + 16) = hi;
        // sBe[128 cols][48B]: k0..9=wconv*PS, k10=dec_ps[b0], k11=dec_ps[b1]
        int col = tid >> 1, kh = tid & 1;
        u32x4 w;
        if (kh == 0) {
            float v0 = wconv[0 * AA + col0 + col] * PS, v1 = wconv[1 * AA + col0 + col] * PS;
            float v2 = wconv[2 * AA + col0 + col] * PS, v3 = wconv[3 * AA + col0 + col] * PS;
            float v4 = wconv[4 * AA + col0 + col] * PS, v5 = wconv[5 * AA + col0 + col] * PS;
            float v6 = wconv[6 * AA + col0 + col] * PS, v7 = wconv[7 * AA + col0 + col] * PS;
            w.x = pkbf(v0, v1); w.y = pkbf(v2, v3); w.z = pkbf(v4, v5); w.w = pkbf(v6, v7);
        } else {
            float v8 = wconv[8 * AA + col0 + col] * PS, v9 = wconv[9 * AA + col0 + col] * PS;
            float d0v = dec_ps[b0 * AA + col0 + col], d1v = dec_ps[b1 * AA + col0 + col];
            w.x = pkbf(v8, v9); w.y = pkbf(d0v, d1v); w.z = 0u; w.w = 0u;
        }
        *(u32x4*)(smem + 12288 + col * 48 + kh * 16) = w;
        if (tid == 0) { *(u32x4*)(smem + ZPAD) = (u32x4){0u, 0u, 0u, 0u}; }
    }
    __syncthreads();

    // ---- head-steps + epilogue ----
    float svj[4];
    bf16x8 be[4];
#pragma unroll
    for (int j = 0; j < 4; ++j) {
        int col = wc * 64 + j * 16 + llo;
        svj[j] = vw[col0 + col];
        u32 off = (lhi < 2) ? (12288u + col * 48 + lhi * 16) : (u32)ZPAD;
        be[j] = *(const bf16x8*)(smem + off);
    }
#pragma unroll
    for (int h = 0; h < 4; ++h) {
#pragma unroll
        for (int i = 0; i < 2; ++i) {
            int rowA = h * 64 + wr * 32 + i * 16 + llo;
            u32 offa = (lhi < 2) ? (rowA * 48 + lhi * 16) : (u32)ZPAD;
            bf16x8 ae = *(const bf16x8*)(smem + offa);
            float ep[4] = {0.f, 0.f, 0.f, 0.f};
#pragma unroll
            for (int j = 0; j < 4; ++j) {
                f32x4 t4 = __builtin_amdgcn_mfma_f32_16x16x32_bf16(ae, be[j], acc[i][j], 0, 0, 0);
#pragma unroll
                for (int r = 0; r < 4; ++r) {
                    float z = exp2f(t4[r]);
                    float p = __builtin_amdgcn_rcpf(1.f + z);
                    ep[r] = fmaf(svj[j], p, ep[r]);
                }
            }
#pragma unroll
            for (int r = 0; r < 4; ++r) {
                float s = ep[r];
                s += __shfl_xor(s, 1);
                s += __shfl_xor(s, 2);
                s += __shfl_xor(s, 4);
                s += __shfl_xor(s, 8);
                if (llo == 0)
                    Q4[((size_t)(bn * HH + h)) * MM + row0 + wr * 32 + i * 16 + lhi * 4 + r] = s;
            }
        }
    }
}

// =================== fin: softmax (blk<128) | ctx (blk>=128) =================
__global__ __launch_bounds__(256) void fin_k(
    const float* __restrict__ Q4, const int* __restrict__ klen,
    const float* __restrict__ aw, const float* __restrict__ value,
    float* __restrict__ aw_new, float* __restrict__ ctx)
{
    __shared__ float fls[1512];
    int blk = blockIdx.x, tid = threadIdx.x;
    if (blk < 128) {
        int h = blk >> 5, b = blk & 31;
        int len = klen[b];
        const float* q0 = Q4 + (size_t)(0 * HH + h) * MM + (size_t)b * TT;
        const float* q1 = Q4 + (size_t)(1 * HH + h) * MM + (size_t)b * TT;
        const float* q2 = Q4 + (size_t)(2 * HH + h) * MM + (size_t)b * TT;
        const float* q3 = Q4 + (size_t)(3 * HH + h) * MM + (size_t)b * TT;
        float* orow = aw_new + (size_t)(h * BB + b) * TT;
        float* rbuf = fls + 1500;
        int lane = tid & 63, wvv = tid >> 6;
        float mx = -3.4e38f;
        for (int t = tid; t < len; t += 256) {
            float e = -2.f * (q0[t] + q1[t] + q2[t] + q3[t]);
            fls[t] = e;
            mx = fmaxf(mx, e);
        }
#pragma unroll
        for (int off = 32; off; off >>= 1) mx = fmaxf(mx, __shfl_xor(mx, off));
        if (lane == 0) rbuf[wvv] = mx;
        __syncthreads();
        mx = fmaxf(fmaxf(rbuf[0], rbuf[1]), fmaxf(rbuf[2], rbuf[3]));
        float sum = 0.f;
        for (int t = tid; t < len; t += 256) {
            float p = __expf(fls[t] - mx);
            fls[t] = p; sum += p;
        }
#pragma unroll
        for (int off = 32; off; off >>= 1) sum += __shfl_xor(sum, off);
        if (lane == 0) rbuf[4 + wvv] = sum;
        __syncthreads();
        float inv = 1.f / (rbuf[4] + rbuf[5] + rbuf[6] + rbuf[7]);
        for (int t = tid; t < TT; t += 256) orow[t] = (t < len) ? fls[t] * inv : 0.f;
    } else {
        int cidx = blk - 128;
        int b = cidx / 25, chunk = cidx - b * 25;
        int c0 = chunk * 60;
        float (*sw)[60] = (float(*)[60])fls;
        if (tid < 240)
            sw[tid / 60][tid % 60] = aw[(size_t)((tid / 60) * BB + b) * TT + c0 + (tid % 60)];
        __syncthreads();
        float a00 = 0, a01 = 0, a10 = 0, a11 = 0, a20 = 0, a21 = 0, a30 = 0, a31 = 0;
        const float* vp = value + ((size_t)b * TT + c0) * DD;
        for (int t = 0; t < 60; ++t) {
            float v0 = vp[(size_t)t * DD + tid];
            float v1 = vp[(size_t)t * DD + tid + 256];
            a00 = fmaf(sw[0][t], v0, a00); a01 = fmaf(sw[0][t], v1, a01);
            a10 = fmaf(sw[1][t], v0, a10); a11 = fmaf(sw[1][t], v1, a11);
            a20 = fmaf(sw[2][t], v0, a20); a21 = fmaf(sw[2][t], v1, a21);
            a30 = fmaf(sw[3][t], v0, a30); a31 = fmaf(sw[3][t], v1, a31);
        }
        atomicAdd(&ctx[(b * HH + 0) * DD + tid], a00);
        atomicAdd(&ctx[(b * HH + 0) * DD + tid + 256], a01);
        atomicAdd(&ctx[(b * HH + 1) * DD + tid], a10);
        atomicAdd(&ctx[(b * HH + 1) * DD + tid + 256], a11);
        atomicAdd(&ctx[(b * HH + 2) * DD + tid], a20);
        atomicAdd(&ctx[(b * HH + 2) * DD + tid + 256], a21);
        atomicAdd(&ctx[(b * HH + 3) * DD + tid], a30);
        atomicAdd(&ctx[(b * HH + 3) * DD + tid + 256], a31);
    }
}

// =================== out[b][d] = ctx_flat[b]·w_out[:,d] + b_out[d] ==========
__global__ __launch_bounds__(512) void out_k(const float* __restrict__ ctx,
                                             const float* __restrict__ wout,
                                             const float* __restrict__ wob,
                                             float* __restrict__ out)
{
    int b0 = blockIdx.x * 4, kc = blockIdx.y;
    int tid = threadIdx.x;
    __shared__ float sc[4][64];
    if (tid < 256) sc[tid >> 6][tid & 63] =
        ctx[(size_t)(b0 + (tid >> 6)) * (HH * DD) + kc * 64 + (tid & 63)];
    __syncthreads();
    float acc0 = 0, acc1 = 0, acc2 = 0, acc3 = 0;
    const float* wp = wout + (size_t)(kc * 64) * DD + tid;
#pragma unroll 8
    for (int kk = 0; kk < 64; ++kk) {
        float w = wp[(size_t)kk * DD];
        acc0 = fmaf(sc[0][kk], w, acc0); acc1 = fmaf(sc[1][kk], w, acc1);
        acc2 = fmaf(sc[2][kk], w, acc2); acc3 = fmaf(sc[3][kk], w, acc3);
    }
    if (kc == 0) {
        float bb = wob[tid];
        acc0 += bb; acc1 += bb; acc2 += bb; acc3 += bb;
    }
    atomicAdd(&out[(b0 + 0) * DD + tid], acc0);
    atomicAdd(&out[(b0 + 1) * DD + tid], acc1);
    atomicAdd(&out[(b0 + 2) * DD + tid], acc2);
    atomicAdd(&out[(b0 + 3) * DD + tid], acc3);
}

extern "C" void kernel_launch(void* const* d_in, const int* in_sizes, int n_in,
                              void* d_out, int out_size, void* d_ws, size_t ws_size,
                              hipStream_t stream) {
    const float* key    = (const float*)d_in[0];
    const int*   klen   = (const int*)  d_in[1];
    const float* value  = (const float*)d_in[2];
    const float* query  = (const float*)d_in[3];
    const float* aw     = (const float*)d_in[4];
    const float* wencW  = (const float*)d_in[5];
    const float* wencb  = (const float*)d_in[6];
    const float* wdecW  = (const float*)d_in[7];
    const float* wconvW = (const float*)d_in[8];
    const float* vW     = (const float*)d_in[9];
    const float* convW  = (const float*)d_in[10];
    const float* woutW  = (const float*)d_in[11];
    const float* woutb  = (const float*)d_in[12];

    float* out    = (float*)d_out;                  // [B*D]
    float* aw_new = out + BB * DD;                  // [H*B*T]

    // workspace (~11.6 MB)
    char* ws = (char*)d_ws;
    u16*   wenc_t = (u16*)ws;                       //   524,288 B
    float* dec_ps = (float*)(ws + 524288);          //    65,536 B
    float* cfeat  = (float*)(ws + 589824);          // 7,680,000 B
    float* Q4     = (float*)(ws + 8269824);         // 3,072,000 B
    float* ctx    = (float*)(ws + 11341824);        //   262,144 B

    prep_k  <<<906, 256, 0, stream>>>(wencW, query, wdecW, wencb, aw, convW,
                                      wenc_t, dec_ps, cfeat, ctx, out);
    gemm_e_k<<<3000, 256, 0, stream>>>(key, wenc_t, dec_ps, cfeat, wconvW, vW, Q4);
    fin_k   <<<928, 256, 0, stream>>>(Q4, klen, aw, value, aw_new, ctx);
    out_k   <<<dim3(8, 32), 512, 0, stream>>>(ctx, woutW, woutb, out);
}